// Round 4
// baseline (648.751 us; speedup 1.0000x reference)
//
#include <hip/hip_runtime.h>

#define NZ 1e-5f
#define PF 8  // prefetch depth in timesteps

__device__ __forceinline__ float fast_exp2(float x) {
#if __has_builtin(__builtin_amdgcn_exp2f)
    return __builtin_amdgcn_exp2f(x);   // v_exp_f32
#else
    return exp2f(x);
#endif
}

__device__ __forceinline__ float fast_log2(float x) {
#if __has_builtin(__builtin_amdgcn_logf)
    return __builtin_amdgcn_logf(x);    // v_log_f32 (base-2)
#else
    return log2f(x);
#endif
}

// Volatile load: pins issue order (volatile ops can't be reordered w.r.t.
// each other => prefetch can't be sunk to its use), waitcnt still lands at use.
__device__ __forceinline__ float vload(const float* p) {
    return *(const volatile float*)p;
}

__global__ __launch_bounds__(64, 1) void hbv_kernel(
    const float* __restrict__ precip,
    const float* __restrict__ temp,
    const float* __restrict__ pet,
    const float* __restrict__ phy,
    float* __restrict__ out,
    int G, int T)
{
    const int g = blockIdx.x * 64 + threadIdx.x;
    if (g >= G) return;

    const float lo[14] = {1.0f, 50.0f, 0.05f, 0.01f, 0.001f, 0.2f, 0.0f,
                          0.0f, -2.5f, 0.5f, 0.0f, 0.0f, 0.3f, 0.0f};
    const float hi[14] = {6.0f, 1000.0f, 0.9f, 0.5f, 0.2f, 1.0f, 10.0f,
                          100.0f, 2.5f, 10.0f, 0.1f, 0.2f, 5.0f, 1.0f};
    float p[14];
#pragma unroll
    for (int i = 0; i < 14; ++i)
        p[i] = lo[i] + phy[g * 14 + i] * (hi[i] - lo[i]);

    const float BETA = p[0], FC = p[1], K0 = p[2], K1 = p[3], K2 = p[4];
    const float LP = p[5], PERCp = p[6], UZL = p[7], TT = p[8], CFMAX = p[9];
    const float CFR = p[10], CWH = p[11], BETAET = p[12], C = p[13];
    const float invFC   = 1.0f / FC;
    const float invLPFC = 1.0f / (LP * FC);
    const float CFRX    = CFR * CFMAX;

    float SP = NZ, MW = NZ, SM = NZ, SUZ = NZ, SLZ = NZ;

    // Named scalar pipeline registers — cannot be demoted to scratch.
#define DECLJ(j) float prb##j, tmb##j, peb##j;
    DECLJ(0) DECLJ(1) DECLJ(2) DECLJ(3) DECLJ(4) DECLJ(5) DECLJ(6) DECLJ(7)

#define LOADJ(j, tt) do {                                                  \
        int tc_ = (tt) < T ? (tt) : (T - 1);                               \
        size_t idx_ = (size_t)tc_ * (size_t)G + (size_t)g;                 \
        prb##j = vload(precip + idx_);                                     \
        tmb##j = vload(temp + idx_);                                       \
        peb##j = vload(pet + idx_);                                        \
    } while (0)

    // Prime the pipeline: steps 0..PF-1 in flight.
    LOADJ(0, 0); LOADJ(1, 1); LOADJ(2, 2); LOADJ(3, 3);
    LOADJ(4, 4); LOADJ(5, 5); LOADJ(6, 6); LOADJ(7, 7);

#define STEPJ(j) do {                                                      \
        const int t = t0 + j;                                              \
        const float pr = prb##j, tm = tmb##j, pe = peb##j;                 \
        LOADJ(j, t + PF); /* refill slot j for t+PF, stays in flight */    \
        const float RAIN = (tm >= TT) ? pr : 0.0f;                         \
        const float SNOW = pr - RAIN;                                      \
        SP += SNOW;                                                        \
        float melt = fminf(fmaxf(CFMAX * (tm - TT), 0.0f), SP);            \
        MW += melt;                                                        \
        SP -= melt;                                                        \
        float refr = fminf(fmaxf(CFRX * (TT - tm), 0.0f), MW);             \
        SP += refr;                                                        \
        MW -= refr;                                                        \
        float tosoil = fmaxf(MW - CWH * SP, 0.0f);                         \
        MW -= tosoil;                                                      \
        float sw = fminf(fast_exp2(BETA * fast_log2(SM * invFC)), 1.0f);   \
        float rt = RAIN + tosoil;                                          \
        float recharge = rt * sw;                                          \
        SM += rt - recharge;                                               \
        float excess = fmaxf(SM - FC, 0.0f);                               \
        SM -= excess;                                                      \
        float ef = fminf(fast_exp2(BETAET * fast_log2(SM * invLPFC)), 1.0f);\
        float ETact = fminf(SM, pe * ef);                                  \
        SM = fmaxf(SM - ETact, NZ);                                        \
        float cap = fminf(SLZ, C * SLZ * (1.0f - fminf(SM * invFC, 1.0f)));\
        SM = fmaxf(SM + cap, NZ);                                          \
        SLZ = fmaxf(SLZ - cap, NZ);                                        \
        SUZ += recharge + excess;                                          \
        float PERC = fminf(SUZ, PERCp);                                    \
        SUZ -= PERC;                                                       \
        float Q0 = K0 * fmaxf(SUZ - UZL, 0.0f);                            \
        SUZ -= Q0;                                                         \
        float Q1 = K1 * SUZ;                                               \
        SUZ -= Q1;                                                         \
        SLZ = fmaxf(SLZ + PERC, 0.0f);                                     \
        float Q2 = K2 * SLZ;                                               \
        SLZ -= Q2;                                                         \
        if (t < T)                                                         \
            out[(size_t)t * (size_t)G + (size_t)g] = Q0 + Q1 + Q2;         \
    } while (0)

    for (int t0 = 0; t0 < T; t0 += PF) {
        STEPJ(0); STEPJ(1); STEPJ(2); STEPJ(3);
        STEPJ(4); STEPJ(5); STEPJ(6); STEPJ(7);
    }
}

extern "C" void kernel_launch(void* const* d_in, const int* in_sizes, int n_in,
                              void* d_out, int out_size, void* d_ws, size_t ws_size,
                              hipStream_t stream) {
    const float* precip = (const float*)d_in[0];
    const float* temp   = (const float*)d_in[1];
    const float* pet    = (const float*)d_in[2];
    const float* phy    = (const float*)d_in[3];
    float* out = (float*)d_out;

    const int G = in_sizes[3] / 14;   // 50000
    const int T = in_sizes[0] / G;    // 365

    dim3 block(64);
    dim3 grid((G + 63) / 64);         // 782 blocks -> all 256 CUs covered
    hbv_kernel<<<grid, block, 0, stream>>>(precip, temp, pet, phy, out, G, T);
}